// Round 6
// baseline (318.927 us; speedup 1.0000x reference)
//
#include <hip/hip_runtime.h>

typedef unsigned short ushort_t;
typedef unsigned int u32;
typedef unsigned long long u64;
typedef __attribute__((ext_vector_type(4))) float f32x4;
typedef __attribute__((ext_vector_type(16))) float f32x16;
typedef __attribute__((ext_vector_type(8))) short s16x8;

__device__ __forceinline__ ushort_t f2bf(float f) {
    u32 u = __float_as_uint(f);
    u32 r = u + 0x7fffu + ((u >> 16) & 1u);
    return (ushort_t)(r >> 16);
}
__device__ __forceinline__ u32 pk_trunc(float a, float b) {
    return (__float_as_uint(a) >> 16) | (__float_as_uint(b) & 0xffff0000u);
}
__device__ __forceinline__ void cp16(const void* g, void* l) {
    __builtin_amdgcn_global_load_lds(
        (const __attribute__((address_space(1))) u32*)g,
        (__attribute__((address_space(3))) u32*)l, 16, 0, 0);
}

// ---------------- fp32 -> bf16 conversion ----------------
__global__ void cvt_qkv(const float* __restrict__ a, const float* __restrict__ b,
                        const float* __restrict__ c, ushort_t* __restrict__ oa,
                        ushort_t* __restrict__ ob, ushort_t* __restrict__ oc) {
    const float* s = blockIdx.y == 0 ? a : (blockIdx.y == 1 ? b : c);
    ushort_t* o = blockIdx.y == 0 ? oa : (blockIdx.y == 1 ? ob : oc);
    int i = (blockIdx.x * 256 + threadIdx.x) * 4;
    float4 v = *(const float4*)(s + i);
    u64 pk = (u64)f2bf(v.x) | ((u64)f2bf(v.y) << 16) |
             ((u64)f2bf(v.z) << 32) | ((u64)f2bf(v.w) << 48);
    *(u64*)(o + i) = pk;
}

__global__ void cvt_w(const float* __restrict__ a, const float* __restrict__ b,
                      const float* __restrict__ c, const float* __restrict__ d,
                      ushort_t* __restrict__ oa, ushort_t* __restrict__ ob,
                      ushort_t* __restrict__ oc, ushort_t* __restrict__ od) {
    const float* s; ushort_t* o;
    switch (blockIdx.y) {
        case 0: s = a; o = oa; break;
        case 1: s = b; o = ob; break;
        case 2: s = c; o = oc; break;
        default: s = d; o = od; break;
    }
    int i = (blockIdx.x * 256 + threadIdx.x) * 4;
    float4 v = *(const float4*)(s + i);
    u64 pk = (u64)f2bf(v.x) | ((u64)f2bf(v.y) << 16) |
             ((u64)f2bf(v.z) << 32) | ((u64)f2bf(v.w) << 48);
    *(u64*)(o + i) = pk;
}

// ---------------- mask -> per-lane fragment-ordered BITS ----------------
// out u32 per (b, kt64, qg32, L): bit (2*mi+p) = mask[q = qg*32 + (L&31)]
// [kt*64 + kpos], kpos = (mi>>3)*32 + ((mi>>1)&3)*8 + (L>>5)*4 + (mi&1)*2 + p.
__global__ __launch_bounds__(256) void prep_mask(const int* __restrict__ m,
                                                 u32* __restrict__ mf) {
    __shared__ u32 ms32[128 * 20];  // [q 128][16 u32 of byte-flags], pad to 20
    const int tid = threadIdx.x;
    const int kt = blockIdx.x, qt = blockIdx.y, b = blockIdx.z;
    const int* mg = m + ((size_t)(b * 2048 + qt * 128)) * 2048 + kt * 64;
#pragma unroll
    for (int rep = 0; rep < 8; rep++) {
        int linear = rep * 256 + tid;
        int row = linear >> 4, ci = linear & 15;
        int4 v = *(const int4*)(mg + (size_t)row * 2048 + ci * 4);
        u32 w = (v.x ? 1u : 0u) | (v.y ? 0x100u : 0u) |
                (v.z ? 0x10000u : 0u) | (v.w ? 0x1000000u : 0u);
        ms32[row * 20 + ci] = w;
    }
    __syncthreads();
    const int qgl = tid >> 6, L = tid & 63, hf = L >> 5, q5 = L & 31;
    const int row = qgl * 32 + q5;
    u32 rw[16];
#pragma unroll
    for (int j = 0; j < 4; j++) {
        uint4 t = *(const uint4*)&ms32[row * 20 + j * 4];
        rw[j * 4] = t.x; rw[j * 4 + 1] = t.y; rw[j * 4 + 2] = t.z; rw[j * 4 + 3] = t.w;
    }
    u32 res = 0;
#pragma unroll
    for (int mi = 0; mi < 16; mi++)
#pragma unroll
        for (int p = 0; p < 2; p++) {
            const int widx = 8 * (mi >> 3) + 2 * ((mi >> 1) & 3) + hf;
            const int shift = 8 * (2 * (mi & 1) + p);
            res |= ((rw[widx] >> shift) & 1u) << (2 * mi + p);
        }
    mf[(((size_t)b * 32 + kt) * 64 + qt * 4 + qgl) * 64 + L] = res;
}

// ---------------- fused q/k/v projection: 128x128 NT GEMM ----------------
// z=0: q scaled by 0.125*log2(e), [B,H,S,64]; z=1: k [B,H,S,64]
// z=2: vT = Wv x^T stored [512][8192] (row = h*64+d, col = b*2048+s)
__global__ __launch_bounds__(256)
void gemm_qkv(const ushort_t* __restrict__ Aq, const ushort_t* __restrict__ Ak,
              const ushort_t* __restrict__ Av, const ushort_t* __restrict__ Wq,
              const ushort_t* __restrict__ Wk, const ushort_t* __restrict__ Wv,
              const float* __restrict__ bq, const float* __restrict__ bk,
              const float* __restrict__ bv, ushort_t* __restrict__ oq,
              ushort_t* __restrict__ ok, ushort_t* __restrict__ ov) {
    constexpr int K = 512;
    const int z = blockIdx.z;
    const ushort_t* A = z == 0 ? Aq : (z == 1 ? Ak : Wv);
    const ushort_t* Bm = z == 0 ? Wq : (z == 1 ? Wk : Av);
    const float* bias = z == 0 ? bq : (z == 1 ? bk : bv);
    ushort_t* out = z == 0 ? oq : (z == 1 ? ok : ov);
    const float scale = z == 0 ? 0.18033688f : 1.0f;  // 0.125*log2(e)
    const int bm = (z == 2) ? blockIdx.y : blockIdx.x;
    const int bn = (z == 2) ? blockIdx.x : blockIdx.y;

    __shared__ ushort_t As[128 * 32];
    __shared__ ushort_t Bs[128 * 32];
    const int tid = threadIdx.x;
    const int wave = tid >> 6, lane = tid & 63, quad = lane >> 4, l16 = lane & 15;
    const int wm = (wave >> 1) * 64, wn = (wave & 1) * 64;

    const ushort_t* Ag = A + (size_t)(bm * 128 + (tid >> 2)) * K + (tid & 3) * 8;
    const ushort_t* Bg = Bm + (size_t)(bn * 128 + (tid >> 2)) * K + (tid & 3) * 8;

    f32x4 acc[4][4];
#pragma unroll
    for (int i = 0; i < 4; i++)
#pragma unroll
        for (int j = 0; j < 4; j++) acc[i][j] = (f32x4){0.f, 0.f, 0.f, 0.f};

    for (int kt = 0; kt < K; kt += 32) {
        __syncthreads();
        cp16(Ag + kt, (char*)As + tid * 16);
        cp16(Ag + 64 * K + kt, (char*)As + 4096 + tid * 16);
        cp16(Bg + kt, (char*)Bs + tid * 16);
        cp16(Bg + 64 * K + kt, (char*)Bs + 4096 + tid * 16);
        __syncthreads();
        s16x8 af[4], bf[4];
#pragma unroll
        for (int i = 0; i < 4; i++)
            af[i] = *(const s16x8*)&As[(wm + i * 16 + l16) * 32 + quad * 8];
#pragma unroll
        for (int j = 0; j < 4; j++)
            bf[j] = *(const s16x8*)&Bs[(wn + j * 16 + l16) * 32 + quad * 8];
#pragma unroll
        for (int i = 0; i < 4; i++)
#pragma unroll
            for (int j = 0; j < 4; j++)
                acc[i][j] = __builtin_amdgcn_mfma_f32_16x16x32_bf16(af[i], bf[j], acc[i][j], 0, 0, 0);
    }

    if (z == 2) {
#pragma unroll
        for (int i = 0; i < 4; i++) {
            const int gm0 = bm * 128 + wm + i * 16 + quad * 4;
            const float4 b4 = *(const float4*)&bias[gm0];
#pragma unroll
            for (int j = 0; j < 4; j++) {
                const int gn = bn * 128 + wn + j * 16 + l16;
                out[(size_t)(gm0 + 0) * 8192 + gn] = f2bf(acc[i][j][0] + b4.x);
                out[(size_t)(gm0 + 1) * 8192 + gn] = f2bf(acc[i][j][1] + b4.y);
                out[(size_t)(gm0 + 2) * 8192 + gn] = f2bf(acc[i][j][2] + b4.z);
                out[(size_t)(gm0 + 3) * 8192 + gn] = f2bf(acc[i][j][3] + b4.w);
            }
        }
    } else {
#pragma unroll
        for (int j = 0; j < 4; j++) {
            const int gn = bn * 128 + wn + j * 16 + l16;
            const float bb = bias[gn];
            const int hh = gn >> 6, dd = gn & 63;
#pragma unroll
            for (int i = 0; i < 4; i++) {
                const int gm0 = bm * 128 + wm + i * 16 + quad * 4;
                const int bi = gm0 >> 11, s0 = gm0 & 2047;
#pragma unroll
                for (int p = 0; p < 4; p++)
                    out[(((size_t)(bi * 8 + hh)) * 2048 + s0 + p) * 64 + dd] =
                        f2bf((acc[i][j][p] + bb) * scale);
            }
        }
    }
}

// ---------------- output projection: 128x64 tile, fp32 out ----------------
__global__ __launch_bounds__(256)
void gemm_out(const ushort_t* __restrict__ A, const ushort_t* __restrict__ W,
              const float* __restrict__ bias, float* __restrict__ out) {
    __shared__ ushort_t As[128 * 32];
    __shared__ ushort_t Bs[64 * 32];
    const int tid = threadIdx.x, bm = blockIdx.x, bn = blockIdx.y;
    const int wave = tid >> 6, lane = tid & 63, quad = lane >> 4, l16 = lane & 15;
    const ushort_t* Ag = A + (size_t)(bm * 128 + (tid >> 2)) * 512 + (tid & 3) * 8;
    const ushort_t* Bg = W + (size_t)(bn * 64 + (tid >> 2)) * 512 + (tid & 3) * 8;

    f32x4 acc[2][4];
#pragma unroll
    for (int i = 0; i < 2; i++)
#pragma unroll
        for (int j = 0; j < 4; j++) acc[i][j] = (f32x4){0.f, 0.f, 0.f, 0.f};

    for (int kt = 0; kt < 512; kt += 32) {
        __syncthreads();
        cp16(Ag + kt, (char*)As + tid * 16);
        cp16(Ag + 64 * 512 + kt, (char*)As + 4096 + tid * 16);
        cp16(Bg + kt, (char*)Bs + tid * 16);
        __syncthreads();
        s16x8 af[2], bf[4];
#pragma unroll
        for (int i = 0; i < 2; i++)
            af[i] = *(const s16x8*)&As[(wave * 32 + i * 16 + l16) * 32 + quad * 8];
#pragma unroll
        for (int j = 0; j < 4; j++)
            bf[j] = *(const s16x8*)&Bs[(j * 16 + l16) * 32 + quad * 8];
#pragma unroll
        for (int i = 0; i < 2; i++)
#pragma unroll
            for (int j = 0; j < 4; j++)
                acc[i][j] = __builtin_amdgcn_mfma_f32_16x16x32_bf16(af[i], bf[j], acc[i][j], 0, 0, 0);
    }

#pragma unroll
    for (int j = 0; j < 4; j++) {
        const int gn = bn * 64 + j * 16 + l16;
        const float bb = bias[gn];
#pragma unroll
        for (int i = 0; i < 2; i++) {
            const int gm0 = bm * 128 + wave * 32 + i * 16 + quad * 4;
#pragma unroll
            for (int p = 0; p < 4; p++)
                out[(size_t)(gm0 + p) * 512 + gn] = acc[i][j][p] + bb;
        }
    }
}

// ---------------- fused attention: 64 q-rows/wave, bit mask, split-K ----------------
// grid (8 qt256, 8 h, 4b*2ks), 256 thr / 4 waves. Wave owns 64 q (2 x 32-q halves).
// K/V frag reads amortized over 2 q-halves; mask = 1 bit/score (2 MB, L2-hot).
__global__ __launch_bounds__(256, 3)
void attn(const ushort_t* __restrict__ q, const ushort_t* __restrict__ k,
          const ushort_t* __restrict__ vT, const u32* __restrict__ mf,
          ushort_t* __restrict__ po, float* __restrict__ pl) {
    __shared__ ushort_t lds[16384];  // Q 32KB aliases {Ks[2] 16KB | Vs[2] 16KB}
    ushort_t* Ks0 = lds;             // per-buffer 4096 ushorts
    ushort_t* Vs0 = lds + 8192;

    const int tid = threadIdx.x;
    const int qt = blockIdx.x, hh = blockIdx.y;
    const int b = blockIdx.z >> 1, ks = blockIdx.z & 1;
    const int w = tid >> 6, L = tid & 63, hf = L >> 5, q5 = L & 31;
    const size_t bh = (size_t)b * 8 + hh;
    const ushort_t* kg = k + bh * 2048 * 64 + (size_t)ks * 65536;
    const ushort_t* vg = vT + (size_t)hh * 64 * 8192 + b * 2048 + ks * 1024;

    // ---- stage Q tile (256 q x 64 d), XOR chunk-swizzled ----
    {
        const ushort_t* qg0 = q + (bh * 2048 + qt * 256) * 64;
#pragma unroll
        for (int i = 0; i < 8; i++) {
            const int lin = i * 256 + tid, sr = lin >> 3, sc = lin & 7;
            cp16(qg0 + (size_t)sr * 64 + ((sc ^ (sr & 7)) * 8), (char*)lds + lin * 16);
        }
    }
    __syncthreads();
    s16x8 Qf[2][4];
#pragma unroll
    for (int qh = 0; qh < 2; qh++) {
        const int row = w * 64 + qh * 32 + q5;
#pragma unroll
        for (int s = 0; s < 4; s++)
            Qf[qh][s] = *(const s16x8*)&lds[row * 64 + (((2 * s + hf) ^ (row & 7)) * 8)];
    }
    __syncthreads();  // all Q reads done before K/V staging overwrites

    // staging maps
    const int lin0 = tid, lin1 = 256 + tid;
    const int sr0 = lin0 >> 3, sc0 = lin0 & 7;
    const int sr1 = lin1 >> 3, sc1 = lin1 & 7;
    const int kc0 = (sc0 ^ (sr0 & 7)) * 8, kc1 = (sc1 ^ (sr1 & 7)) * 8;

    cp16(kg + (size_t)sr0 * 64 + kc0, (char*)Ks0 + lin0 * 16);
    cp16(kg + (size_t)sr1 * 64 + kc1, (char*)Ks0 + lin1 * 16);
    cp16(vg + (size_t)sr0 * 8192 + kc0, (char*)Vs0 + lin0 * 16);
    cp16(vg + (size_t)sr1 * 8192 + kc1, (char*)Vs0 + lin1 * 16);

    f32x16 O[2][2];
#pragma unroll
    for (int a = 0; a < 2; a++)
#pragma unroll
        for (int d = 0; d < 2; d++)
#pragma unroll
            for (int i = 0; i < 16; i++) O[a][d][i] = 0.f;
    float rs[2] = {0.f, 0.f};

    const u32* mrow = mf + (((size_t)b * 32 + ks * 16) * 64 + qt * 8 + w * 2) * 64 + L;

    for (int it = 0; it < 16; ++it) {
        const int cur = it & 1;
        __syncthreads();  // buffer[cur] staged
        if (it + 1 < 16) {
            const ushort_t* kn = kg + (size_t)(it + 1) * 4096;
            const ushort_t* vn = vg + (size_t)(it + 1) * 64;
            ushort_t* kd = Ks0 + (1 - cur) * 4096;
            ushort_t* vd = Vs0 + (1 - cur) * 4096;
            cp16(kn + (size_t)sr0 * 64 + kc0, (char*)kd + lin0 * 16);
            cp16(kn + (size_t)sr1 * 64 + kc1, (char*)kd + lin1 * 16);
            cp16(vn + (size_t)sr0 * 8192 + kc0, (char*)vd + lin0 * 16);
            cp16(vn + (size_t)sr1 * 8192 + kc1, (char*)vd + lin1 * 16);
        }
        const ushort_t* Kc = Ks0 + cur * 4096;
        const ushort_t* Vc = Vs0 + cur * 4096;

        // mask bits: one u32 per q-half (L2-hot, 2 MB buffer)
        const u32 m0 = mrow[(size_t)it * 4096];
        const u32 m1 = mrow[(size_t)it * 4096 + 64];

        // S^T = K Q^T, per (kpos-half mt, q-half qh); exp+mask+pack immediately
        u32 P[2][16];
#pragma unroll
        for (int mt = 0; mt < 2; mt++) {
            s16x8 kf[4];
#pragma unroll
            for (int s = 0; s < 4; s++)
                kf[s] = *(const s16x8*)&Kc[(mt * 32 + q5) * 64 + (((2 * s + hf) ^ (q5 & 7)) * 8)];
#pragma unroll
            for (int qh = 0; qh < 2; qh++) {
                f32x16 c;
#pragma unroll
                for (int i = 0; i < 16; i++) c[i] = 0.f;
#pragma unroll
                for (int s = 0; s < 4; s++)
                    c = __builtin_amdgcn_mfma_f32_32x32x16_bf16(kf[s], Qf[qh][s], c, 0, 0, 0);
                const u32 mm = qh ? m1 : m0;
#pragma unroll
                for (int jl = 0; jl < 8; jl++) {
                    const int reg = (jl >> 1) * 4 + (jl & 1) * 2;
                    const int bi = 2 * (mt * 8 + jl);
                    const u32 am0 = (u32)((int)(mm << (31 - bi)) >> 31);
                    const u32 am1 = (u32)((int)(mm << (30 - bi)) >> 31);
                    float e0 = __builtin_amdgcn_exp2f(c[reg]);
                    float e1 = __builtin_amdgcn_exp2f(c[reg + 1]);
                    e0 = __uint_as_float(__float_as_uint(e0) & am0);
                    e1 = __uint_as_float(__float_as_uint(e1) & am1);
                    rs[qh] += e0 + e1;
                    P[qh][mt * 8 + jl] = pk_trunc(e0, e1);
                }
            }
        }

        // O^T += V^T P^T  (P C->B frag via shfl_xor 32; V frags shared across qh)
#pragma unroll
        for (int s = 0; s < 4; s++) {
            s16x8 Pf[2];
#pragma unroll
            for (int qh = 0; qh < 2; qh++) {
                const u32 a0 = P[qh][4 * s], a1 = P[qh][4 * s + 1];
                const u32 b0 = P[qh][4 * s + 2], b1 = P[qh][4 * s + 3];
                const u32 r0 = __shfl_xor((int)(hf ? a0 : b0), 32);
                const u32 r1 = __shfl_xor((int)(hf ? a1 : b1), 32);
                union { uint4 u; s16x8 v; } pu;
                pu.u.x = hf ? r0 : a0;
                pu.u.y = hf ? r1 : a1;
                pu.u.z = hf ? b0 : r0;
                pu.u.w = hf ? b1 : r1;
                Pf[qh] = pu.v;
            }
            const s16x8 vf0 = *(const s16x8*)&Vc[q5 * 64 + (((2 * s + hf) ^ (q5 & 7)) * 8)];
            const s16x8 vf1 = *(const s16x8*)&Vc[(32 + q5) * 64 + (((2 * s + hf) ^ (q5 & 7)) * 8)];
            O[0][0] = __builtin_amdgcn_mfma_f32_32x32x16_bf16(vf0, Pf[0], O[0][0], 0, 0, 0);
            O[1][0] = __builtin_amdgcn_mfma_f32_32x32x16_bf16(vf0, Pf[1], O[1][0], 0, 0, 0);
            O[0][1] = __builtin_amdgcn_mfma_f32_32x32x16_bf16(vf1, Pf[0], O[0][1], 0, 0, 0);
            O[1][1] = __builtin_amdgcn_mfma_f32_32x32x16_bf16(vf1, Pf[1], O[1][1], 0, 0, 0);
        }
    }

#pragma unroll
    for (int qh = 0; qh < 2; qh++) {
        const float rst = rs[qh] + __shfl_xor(rs[qh], 32);
        const int qrow = qt * 256 + w * 64 + qh * 32 + q5;
        if (hf == 0)
            pl[(((size_t)ks * 4 + b) * 8 + hh) * 2048 + qrow] = rst;
        ushort_t* por = po + ((size_t)(ks * 4 + b) * 2048 + qrow) * 512 + hh * 64;
#pragma unroll
        for (int dh = 0; dh < 2; dh++)
#pragma unroll
            for (int r4 = 0; r4 < 4; r4++) {
                const int d = dh * 32 + r4 * 8 + hf * 4;
                const float v0 = O[qh][dh][r4 * 4 + 0];
                const float v1 = O[qh][dh][r4 * 4 + 1];
                const float v2 = O[qh][dh][r4 * 4 + 2];
                const float v3 = O[qh][dh][r4 * 4 + 3];
                u32 lo = (u32)f2bf(v0) | ((u32)f2bf(v1) << 16);
                u32 hi = (u32)f2bf(v2) | ((u32)f2bf(v3) << 16);
                *(uint2*)(por + d) = make_uint2(lo, hi);
            }
    }
}

// ---------------- combine bf16 split-K partials -> bf16 x ----------------
__global__ __launch_bounds__(256)
void combine(const ushort_t* __restrict__ po, const float* __restrict__ pl,
             ushort_t* __restrict__ x) {
    const size_t i = ((size_t)blockIdx.x * 256 + threadIdx.x) * 8;
    const size_t row = i >> 9;          // b*2048 + s
    const int c = (int)(i & 511), h = c >> 6;
    const int b = (int)(row >> 11);
    const int s = (int)(row & 2047);
    const float l0 = pl[(((size_t)b) * 8 + h) * 2048 + s];
    const float l1 = pl[(((size_t)4 + b) * 8 + h) * 2048 + s];
    const float inv = 1.0f / (l0 + l1);
    const ushort_t* p0 = po + row * 512 + c;
    const ushort_t* p1 = p0 + (size_t)4 * 2048 * 512;
    uint4 a = *(const uint4*)p0;
    uint4 bb = *(const uint4*)p1;
    u32 ua[4] = {a.x, a.y, a.z, a.w}, ub[4] = {bb.x, bb.y, bb.z, bb.w};
    u32 o[4];
#pragma unroll
    for (int j = 0; j < 4; j++) {
        const float s0 = (__uint_as_float(ua[j] << 16) + __uint_as_float(ub[j] << 16)) * inv;
        const float s1 = (__uint_as_float(ua[j] & 0xffff0000u) +
                          __uint_as_float(ub[j] & 0xffff0000u)) * inv;
        o[j] = (u32)f2bf(s0) | ((u32)f2bf(s1) << 16);
    }
    *(uint4*)(x + i) = make_uint4(o[0], o[1], o[2], o[3]);
}

// ---------------- launch ----------------
extern "C" void kernel_launch(void* const* d_in, const int* in_sizes, int n_in,
                              void* d_out, int out_size, void* d_ws, size_t ws_size,
                              hipStream_t stream) {
    const float* query = (const float*)d_in[0];
    const float* key_ = (const float*)d_in[1];
    const float* value = (const float*)d_in[2];
    const int* mask = (const int*)d_in[3];
    const float* Wq = (const float*)d_in[4];
    const float* bq = (const float*)d_in[5];
    const float* Wk = (const float*)d_in[6];
    const float* bk = (const float*)d_in[7];
    const float* Wv = (const float*)d_in[8];
    const float* bv = (const float*)d_in[9];
    const float* Wo = (const float*)d_in[10];
    const float* bo = (const float*)d_in[11];

    const size_t E = 4194304;  // 8192*512
    const size_t W = 262144;   // 512*512
    ushort_t* qb = (ushort_t*)d_ws;
    ushort_t* kb = qb + E;
    ushort_t* vb = kb + E;
    ushort_t* Wqb = vb + E;
    ushort_t* Wkb = Wqb + W;
    ushort_t* Wvb = Wkb + W;
    ushort_t* Wob = Wvb + W;
    u32* mbits = (u32*)(Wob + W);              // 4*32*64*64 u32 = 2 MB
    ushort_t* qp = (ushort_t*)(mbits + (size_t)4 * 32 * 64 * 64);
    ushort_t* kp = qp + E;
    ushort_t* vTp = kp + E;   // [512][8192]
    ushort_t* xp = vTp + E;
    ushort_t* po = xp + E;                      // bf16, 2*4*2048*512
    float* pl = (float*)(po + (size_t)2 * 4 * 2048 * 512);  // 2*4*8*2048 fp32

    cvt_qkv<<<dim3(4096, 3), 256, 0, stream>>>(query, key_, value, qb, kb, vb);
    cvt_w<<<dim3(256, 4), 256, 0, stream>>>(Wq, Wk, Wv, Wo, Wqb, Wkb, Wvb, Wob);
    prep_mask<<<dim3(32, 16, 4), 256, 0, stream>>>(mask, mbits);

    gemm_qkv<<<dim3(64, 4, 3), 256, 0, stream>>>(qb, kb, vb, Wqb, Wkb, Wvb,
                                                 bq, bk, bv, qp, kp, vTp);

    attn<<<dim3(8, 8, 8), 256, 0, stream>>>(qp, kp, vTp, mbits, po, pl);

    combine<<<dim3(2048), 256, 0, stream>>>(po, pl, xp);

    gemm_out<<<dim3(64, 8), 256, 0, stream>>>(xp, Wob, bo, (float*)d_out);
}

// Round 7
// 262.000 us; speedup vs baseline: 1.2173x; 1.2173x over previous
//
#include <hip/hip_runtime.h>

typedef unsigned short ushort_t;
typedef unsigned int u32;
typedef unsigned long long u64;
typedef __attribute__((ext_vector_type(4))) float f32x4;
typedef __attribute__((ext_vector_type(16))) float f32x16;
typedef __attribute__((ext_vector_type(8))) short s16x8;

__device__ __forceinline__ ushort_t f2bf(float f) {
    u32 u = __float_as_uint(f);
    u32 r = u + 0x7fffu + ((u >> 16) & 1u);
    return (ushort_t)(r >> 16);
}
__device__ __forceinline__ u32 pk_trunc(float a, float b) {
    return (__float_as_uint(a) >> 16) | (__float_as_uint(b) & 0xffff0000u);
}
__device__ __forceinline__ void cp16(const void* g, void* l) {
    __builtin_amdgcn_global_load_lds(
        (const __attribute__((address_space(1))) u32*)g,
        (__attribute__((address_space(3))) u32*)l, 16, 0, 0);
}

// ---------------- fused prep: bf16 casts + bit-mask, one launch ----------------
// blocks [0,12288): cvt q/k/v; [12288,13312): cvt W; [13312,15360): mask bits
__global__ __launch_bounds__(256)
void prep_all(const float* __restrict__ qf, const float* __restrict__ kf,
              const float* __restrict__ vf, const float* __restrict__ Wq,
              const float* __restrict__ Wk, const float* __restrict__ Wv,
              const float* __restrict__ Wo, const int* __restrict__ m,
              ushort_t* __restrict__ oq, ushort_t* __restrict__ ok,
              ushort_t* __restrict__ ov, ushort_t* __restrict__ oWq,
              ushort_t* __restrict__ oWk, ushort_t* __restrict__ oWv,
              ushort_t* __restrict__ oWo, u32* __restrict__ mf) {
    const int bid = blockIdx.x;
    const int tid = threadIdx.x;
    if (bid < 13312) {
        const float* s; ushort_t* o; int i;
        if (bid < 12288) {
            const int part = bid >> 12, bx = bid & 4095;
            s = part == 0 ? qf : (part == 1 ? kf : vf);
            o = part == 0 ? oq : (part == 1 ? ok : ov);
            i = (bx * 256 + tid) * 4;
        } else {
            const int r = bid - 12288;
            const int part = r >> 8, bx = r & 255;
            s = part == 0 ? Wq : (part == 1 ? Wk : (part == 2 ? Wv : Wo));
            o = part == 0 ? oWq : (part == 1 ? oWk : (part == 2 ? oWv : oWo));
            i = (bx * 256 + tid) * 4;
        }
        float4 v = *(const float4*)(s + i);
        u64 pk = (u64)f2bf(v.x) | ((u64)f2bf(v.y) << 16) |
                 ((u64)f2bf(v.z) << 32) | ((u64)f2bf(v.w) << 48);
        *(u64*)(o + i) = pk;
    } else {
        // mask -> fragment-ordered bits: u32 per (b, kt64, g32=q/32, lane)
        // bit (2*mi+p): kpos = (mi>>3)*32 + ((mi>>1)&3)*8 + (L>>5)*4 + (mi&1)*2 + p
        __shared__ u32 ms32[128 * 20];
        const int r = bid - 13312;
        const int kt = r & 31, qt = (r >> 5) & 15, b = r >> 9;
        const int* mg = m + ((size_t)(b * 2048 + qt * 128)) * 2048 + kt * 64;
#pragma unroll
        for (int rep = 0; rep < 8; rep++) {
            int linear = rep * 256 + tid;
            int row = linear >> 4, ci = linear & 15;
            int4 v = *(const int4*)(mg + (size_t)row * 2048 + ci * 4);
            u32 w = (v.x ? 1u : 0u) | (v.y ? 0x100u : 0u) |
                    (v.z ? 0x10000u : 0u) | (v.w ? 0x1000000u : 0u);
            ms32[row * 20 + ci] = w;
        }
        __syncthreads();
        const int qgl = tid >> 6, L = tid & 63, hf = L >> 5, q5 = L & 31;
        const int row = qgl * 32 + q5;
        u32 rw[16];
#pragma unroll
        for (int j = 0; j < 4; j++) {
            uint4 t = *(const uint4*)&ms32[row * 20 + j * 4];
            rw[j * 4] = t.x; rw[j * 4 + 1] = t.y; rw[j * 4 + 2] = t.z; rw[j * 4 + 3] = t.w;
        }
        u32 res = 0;
#pragma unroll
        for (int mi = 0; mi < 16; mi++)
#pragma unroll
            for (int p = 0; p < 2; p++) {
                const int widx = 8 * (mi >> 3) + 2 * ((mi >> 1) & 3) + hf;
                const int shift = 8 * (2 * (mi & 1) + p);
                res |= ((rw[widx] >> shift) & 1u) << (2 * mi + p);
            }
        mf[(((size_t)b * 32 + kt) * 64 + qt * 4 + qgl) * 64 + L] = res;
    }
}

// ---------------- fused q/k/v projection: 128x128 NT GEMM ----------------
// z=0: q scaled by 0.125*log2(e), [B,H,S,64]; z=1: k [B,H,S,64]
// z=2: vT = Wv x^T stored [512][8192]
__global__ __launch_bounds__(256)
void gemm_qkv(const ushort_t* __restrict__ Aq, const ushort_t* __restrict__ Ak,
              const ushort_t* __restrict__ Av, const ushort_t* __restrict__ Wq,
              const ushort_t* __restrict__ Wk, const ushort_t* __restrict__ Wv,
              const float* __restrict__ bq, const float* __restrict__ bk,
              const float* __restrict__ bv, ushort_t* __restrict__ oq,
              ushort_t* __restrict__ ok, ushort_t* __restrict__ ov) {
    constexpr int K = 512;
    const int z = blockIdx.z;
    const ushort_t* A = z == 0 ? Aq : (z == 1 ? Ak : Wv);
    const ushort_t* Bm = z == 0 ? Wq : (z == 1 ? Wk : Av);
    const float* bias = z == 0 ? bq : (z == 1 ? bk : bv);
    ushort_t* out = z == 0 ? oq : (z == 1 ? ok : ov);
    const float scale = z == 0 ? 0.18033688f : 1.0f;  // 0.125*log2(e)
    const int bm = (z == 2) ? blockIdx.y : blockIdx.x;
    const int bn = (z == 2) ? blockIdx.x : blockIdx.y;

    __shared__ ushort_t As[128 * 32];
    __shared__ ushort_t Bs[128 * 32];
    const int tid = threadIdx.x;
    const int wave = tid >> 6, lane = tid & 63, quad = lane >> 4, l16 = lane & 15;
    const int wm = (wave >> 1) * 64, wn = (wave & 1) * 64;

    const ushort_t* Ag = A + (size_t)(bm * 128 + (tid >> 2)) * K + (tid & 3) * 8;
    const ushort_t* Bg = Bm + (size_t)(bn * 128 + (tid >> 2)) * K + (tid & 3) * 8;

    f32x4 acc[4][4];
#pragma unroll
    for (int i = 0; i < 4; i++)
#pragma unroll
        for (int j = 0; j < 4; j++) acc[i][j] = (f32x4){0.f, 0.f, 0.f, 0.f};

    for (int kt = 0; kt < K; kt += 32) {
        __syncthreads();
        cp16(Ag + kt, (char*)As + tid * 16);
        cp16(Ag + 64 * K + kt, (char*)As + 4096 + tid * 16);
        cp16(Bg + kt, (char*)Bs + tid * 16);
        cp16(Bg + 64 * K + kt, (char*)Bs + 4096 + tid * 16);
        __syncthreads();
        s16x8 af[4], bf[4];
#pragma unroll
        for (int i = 0; i < 4; i++)
            af[i] = *(const s16x8*)&As[(wm + i * 16 + l16) * 32 + quad * 8];
#pragma unroll
        for (int j = 0; j < 4; j++)
            bf[j] = *(const s16x8*)&Bs[(wn + j * 16 + l16) * 32 + quad * 8];
#pragma unroll
        for (int i = 0; i < 4; i++)
#pragma unroll
            for (int j = 0; j < 4; j++)
                acc[i][j] = __builtin_amdgcn_mfma_f32_16x16x32_bf16(af[i], bf[j], acc[i][j], 0, 0, 0);
    }

    if (z == 2) {
#pragma unroll
        for (int i = 0; i < 4; i++) {
            const int gm0 = bm * 128 + wm + i * 16 + quad * 4;
            const float4 b4 = *(const float4*)&bias[gm0];
#pragma unroll
            for (int j = 0; j < 4; j++) {
                const int gn = bn * 128 + wn + j * 16 + l16;
                out[(size_t)(gm0 + 0) * 8192 + gn] = f2bf(acc[i][j][0] + b4.x);
                out[(size_t)(gm0 + 1) * 8192 + gn] = f2bf(acc[i][j][1] + b4.y);
                out[(size_t)(gm0 + 2) * 8192 + gn] = f2bf(acc[i][j][2] + b4.z);
                out[(size_t)(gm0 + 3) * 8192 + gn] = f2bf(acc[i][j][3] + b4.w);
            }
        }
    } else {
#pragma unroll
        for (int j = 0; j < 4; j++) {
            const int gn = bn * 128 + wn + j * 16 + l16;
            const float bb = bias[gn];
            const int hh = gn >> 6, dd = gn & 63;
#pragma unroll
            for (int i = 0; i < 4; i++) {
                const int gm0 = bm * 128 + wm + i * 16 + quad * 4;
                const int bi = gm0 >> 11, s0 = gm0 & 2047;
#pragma unroll
                for (int p = 0; p < 4; p++)
                    out[(((size_t)(bi * 8 + hh)) * 2048 + s0 + p) * 64 + dd] =
                        f2bf((acc[i][j][p] + bb) * scale);
            }
        }
    }
}

// ---------------- fused attention: r5 structure + bit mask, no ones-MFMA ----------------
// grid (16 qt128, 8 h, 4b*2ks), 256 thr / 4 waves. Wave owns 32 q (q = lane&31).
__global__ __launch_bounds__(256, 4)
void attn(const ushort_t* __restrict__ q, const ushort_t* __restrict__ k,
          const ushort_t* __restrict__ vT, const u32* __restrict__ mf,
          ushort_t* __restrict__ po, float* __restrict__ pl) {
    __shared__ ushort_t Ks[2][64 * 64];  // double-buffered, XOR chunk-swizzled
    __shared__ ushort_t Vs[2][64 * 64];

    const int tid = threadIdx.x;
    const int qt = blockIdx.x, hh = blockIdx.y;
    const int b = blockIdx.z >> 1, ks = blockIdx.z & 1;
    const int w = tid >> 6, L = tid & 63, hf = L >> 5, q5 = L & 31;
    const size_t bh = (size_t)b * 8 + hh;
    const ushort_t* qg = q + (bh * 2048 + qt * 128 + w * 32) * 64;
    const ushort_t* kg = k + bh * 2048 * 64 + (size_t)ks * 65536;
    const ushort_t* vg = vT + (size_t)hh * 64 * 8192 + b * 2048 + ks * 1024;
    const u32* mg = mf + (((size_t)b * 32 + ks * 16) * 64 + qt * 4 + w) * 64 + L;

    const int lin0 = tid, lin1 = 256 + tid;
    const int sr0 = lin0 >> 3, sc0 = lin0 & 7;
    const int sr1 = lin1 >> 3, sc1 = lin1 & 7;
    const int kc0 = (sc0 ^ (sr0 & 7)) * 8, kc1 = (sc1 ^ (sr1 & 7)) * 8;

    cp16(kg + (size_t)sr0 * 64 + kc0, (char*)Ks[0] + lin0 * 16);
    cp16(kg + (size_t)sr1 * 64 + kc1, (char*)Ks[0] + lin1 * 16);
    cp16(vg + (size_t)sr0 * 8192 + kc0, (char*)Vs[0] + lin0 * 16);
    cp16(vg + (size_t)sr1 * 8192 + kc1, (char*)Vs[0] + lin1 * 16);

    s16x8 Qf[4];
#pragma unroll
    for (int s = 0; s < 4; s++)
        Qf[s] = *(const s16x8*)(qg + q5 * 64 + s * 16 + hf * 8);

    f32x16 O0, O1;
#pragma unroll
    for (int i = 0; i < 16; i++) { O0[i] = 0.f; O1[i] = 0.f; }
    float rsl = 0.f;

    for (int it = 0; it < 16; ++it) {
        const int cur = it & 1;
        __syncthreads();  // buffer[cur] staged
        if (it + 1 < 16) {
            const ushort_t* kn = kg + (size_t)(it + 1) * 4096;
            const ushort_t* vn = vg + (size_t)(it + 1) * 64;
            cp16(kn + (size_t)sr0 * 64 + kc0, (char*)Ks[1 - cur] + lin0 * 16);
            cp16(kn + (size_t)sr1 * 64 + kc1, (char*)Ks[1 - cur] + lin1 * 16);
            cp16(vn + (size_t)sr0 * 8192 + kc0, (char*)Vs[1 - cur] + lin0 * 16);
            cp16(vn + (size_t)sr1 * 8192 + kc1, (char*)Vs[1 - cur] + lin1 * 16);
        }

        const u32 mm = mg[(size_t)it * 4096];  // bit mask, L2-hot (2 MB total)

        f32x16 c0, c1;
#pragma unroll
        for (int i = 0; i < 16; i++) { c0[i] = 0.f; c1[i] = 0.f; }
#pragma unroll
        for (int s = 0; s < 4; s++) {
            const s16x8 kf0 = *(const s16x8*)&Ks[cur][q5 * 64 + (((2 * s + hf) ^ (q5 & 7)) * 8)];
            c0 = __builtin_amdgcn_mfma_f32_32x32x16_bf16(kf0, Qf[s], c0, 0, 0, 0);
        }
#pragma unroll
        for (int s = 0; s < 4; s++) {
            const s16x8 kf1 = *(const s16x8*)&Ks[cur][(32 + q5) * 64 + (((2 * s + hf) ^ (q5 & 7)) * 8)];
            c1 = __builtin_amdgcn_mfma_f32_32x32x16_bf16(kf1, Qf[s], c1, 0, 0, 0);
        }

        u32 P[16];
#pragma unroll
        for (int mi = 0; mi < 16; mi++) {
            const int reg = ((mi >> 1) & 3) * 4 + (mi & 1) * 2;
            const u32 am0 = (u32)((int)(mm << (31 - 2 * mi)) >> 31);
            const u32 am1 = (u32)((int)(mm << (30 - 2 * mi)) >> 31);
            const float s0 = (mi < 8) ? c0[reg] : c1[reg];
            const float s1 = (mi < 8) ? c0[reg + 1] : c1[reg + 1];
            float e0 = __builtin_amdgcn_exp2f(s0);
            float e1 = __builtin_amdgcn_exp2f(s1);
            e0 = __uint_as_float(__float_as_uint(e0) & am0);
            e1 = __uint_as_float(__float_as_uint(e1) & am1);
            rsl += e0 + e1;
            P[mi] = pk_trunc(e0, e1);
        }

#pragma unroll
        for (int s = 0; s < 4; s++) {
            const u32 a0 = P[4 * s], a1 = P[4 * s + 1];
            const u32 b0 = P[4 * s + 2], b1 = P[4 * s + 3];
            const u32 r0 = __shfl_xor((int)(hf ? a0 : b0), 32);
            const u32 r1 = __shfl_xor((int)(hf ? a1 : b1), 32);
            union { uint4 u; s16x8 v; } pu;
            pu.u.x = hf ? r0 : a0;
            pu.u.y = hf ? r1 : a1;
            pu.u.z = hf ? b0 : r0;
            pu.u.w = hf ? b1 : r1;
            const s16x8 Pf = pu.v;
            const s16x8 vf0 = *(const s16x8*)&Vs[cur][q5 * 64 + (((2 * s + hf) ^ (q5 & 7)) * 8)];
            const s16x8 vf1 = *(const s16x8*)&Vs[cur][(32 + q5) * 64 + (((2 * s + hf) ^ (q5 & 7)) * 8)];
            O0 = __builtin_amdgcn_mfma_f32_32x32x16_bf16(vf0, Pf, O0, 0, 0, 0);
            O1 = __builtin_amdgcn_mfma_f32_32x32x16_bf16(vf1, Pf, O1, 0, 0, 0);
        }
    }

    const float rst = rsl + __shfl_xor(rsl, 32);
    const int qrow = qt * 128 + w * 32 + q5;
    if (hf == 0)
        pl[(((size_t)ks * 4 + b) * 8 + hh) * 2048 + qrow] = rst;
    ushort_t* por = po + ((size_t)(ks * 4 + b) * 2048 + qrow) * 512 + hh * 64;
#pragma unroll
    for (int dh = 0; dh < 2; dh++)
#pragma unroll
        for (int r4 = 0; r4 < 4; r4++) {
            const int d = dh * 32 + r4 * 8 + hf * 4;
            const float v0 = dh ? O1[r4 * 4 + 0] : O0[r4 * 4 + 0];
            const float v1 = dh ? O1[r4 * 4 + 1] : O0[r4 * 4 + 1];
            const float v2 = dh ? O1[r4 * 4 + 2] : O0[r4 * 4 + 2];
            const float v3 = dh ? O1[r4 * 4 + 3] : O0[r4 * 4 + 3];
            u32 lo = (u32)f2bf(v0) | ((u32)f2bf(v1) << 16);
            u32 hi = (u32)f2bf(v2) | ((u32)f2bf(v3) << 16);
            *(uint2*)(por + d) = make_uint2(lo, hi);
        }
}

// ---------------- output projection with fused split-K combine ----------------
// A-tile staged by VALU: x[row][ch] = (po0 + po1) * inv_l(row, h=ch/64)
__global__ __launch_bounds__(256)
void gemm_out(const ushort_t* __restrict__ po, const float* __restrict__ pl,
              const ushort_t* __restrict__ W, const float* __restrict__ bias,
              float* __restrict__ out) {
    __shared__ ushort_t As[128 * 32];
    __shared__ ushort_t Bs[64 * 32];
    __shared__ float lls[8 * 128];
    const int tid = threadIdx.x, bm = blockIdx.x, bn = blockIdx.y;
    const int wave = tid >> 6, lane = tid & 63, quad = lane >> 4, l16 = lane & 15;

    // inverse-l table for this block's 128 rows x 8 heads
#pragma unroll
    for (int rep = 0; rep < 4; rep++) {
        const int idx = rep * 256 + tid;
        const int h = idx >> 7, r = idx & 127;
        const int gm = bm * 128 + r, b = gm >> 11, s = gm & 2047;
        const float l0 = pl[((size_t)b * 8 + h) * 2048 + s];
        const float l1 = pl[((size_t)(4 + b) * 8 + h) * 2048 + s];
        lls[idx] = 1.0f / (l0 + l1);
    }

    const ushort_t* Bg = W + (size_t)(bn * 64 + (tid >> 2)) * 512 + (tid & 3) * 8;
    const int r0 = tid >> 2, c8 = (tid & 3) * 8;

    f32x4 acc[2][4];
#pragma unroll
    for (int i = 0; i < 2; i++)
#pragma unroll
        for (int j = 0; j < 4; j++) acc[i][j] = (f32x4){0.f, 0.f, 0.f, 0.f};

    for (int kt = 0; kt < 512; kt += 32) {
        __syncthreads();
        cp16(Bg + kt, (char*)Bs + tid * 16);
        const int hidx = kt >> 6;
#pragma unroll
        for (int half = 0; half < 2; half++) {
            const int r = r0 + half * 64;
            const ushort_t* p0 = po + (size_t)(bm * 128 + r) * 512 + kt + c8;
            const ushort_t* p1 = p0 + (size_t)4 * 2048 * 512;
            const uint4 ua = *(const uint4*)p0;
            const uint4 ub = *(const uint4*)p1;
            const float inv = lls[hidx * 128 + r];
            const u32 xa[4] = {ua.x, ua.y, ua.z, ua.w};
            const u32 xb[4] = {ub.x, ub.y, ub.z, ub.w};
            u32 wo[4];
#pragma unroll
            for (int j = 0; j < 4; j++) {
                const float lo = (__uint_as_float(xa[j] << 16) +
                                  __uint_as_float(xb[j] << 16)) * inv;
                const float hi = (__uint_as_float(xa[j] & 0xffff0000u) +
                                  __uint_as_float(xb[j] & 0xffff0000u)) * inv;
                wo[j] = (u32)f2bf(lo) | ((u32)f2bf(hi) << 16);
            }
            *(uint4*)&As[r * 32 + c8] = make_uint4(wo[0], wo[1], wo[2], wo[3]);
        }
        __syncthreads();
        s16x8 af[2], bf[4];
#pragma unroll
        for (int i = 0; i < 2; i++)
            af[i] = *(const s16x8*)&As[(wave * 32 + i * 16 + l16) * 32 + quad * 8];
#pragma unroll
        for (int j = 0; j < 4; j++)
            bf[j] = *(const s16x8*)&Bs[(j * 16 + l16) * 32 + quad * 8];
#pragma unroll
        for (int i = 0; i < 2; i++)
#pragma unroll
            for (int j = 0; j < 4; j++)
                acc[i][j] = __builtin_amdgcn_mfma_f32_16x16x32_bf16(af[i], bf[j], acc[i][j], 0, 0, 0);
    }

#pragma unroll
    for (int j = 0; j < 4; j++) {
        const int gn = bn * 64 + j * 16 + l16;
        const float bb = bias[gn];
#pragma unroll
        for (int i = 0; i < 2; i++) {
            const int gm0 = bm * 128 + wave * 32 + i * 16 + quad * 4;
#pragma unroll
            for (int p = 0; p < 4; p++)
                out[(size_t)(gm0 + p) * 512 + gn] = acc[i][j][p] + bb;
        }
    }
}

// ---------------- launch ----------------
extern "C" void kernel_launch(void* const* d_in, const int* in_sizes, int n_in,
                              void* d_out, int out_size, void* d_ws, size_t ws_size,
                              hipStream_t stream) {
    const float* query = (const float*)d_in[0];
    const float* key_ = (const float*)d_in[1];
    const float* value = (const float*)d_in[2];
    const int* mask = (const int*)d_in[3];
    const float* Wq = (const float*)d_in[4];
    const float* bq = (const float*)d_in[5];
    const float* Wk = (const float*)d_in[6];
    const float* bk = (const float*)d_in[7];
    const float* Wv = (const float*)d_in[8];
    const float* bv = (const float*)d_in[9];
    const float* Wo = (const float*)d_in[10];
    const float* bo = (const float*)d_in[11];

    const size_t E = 4194304;  // 8192*512
    const size_t W = 262144;   // 512*512
    ushort_t* qb = (ushort_t*)d_ws;
    ushort_t* kb = qb + E;
    ushort_t* vb = kb + E;
    ushort_t* Wqb = vb + E;
    ushort_t* Wkb = Wqb + W;
    ushort_t* Wvb = Wkb + W;
    ushort_t* Wob = Wvb + W;
    u32* mbits = (u32*)(Wob + W);              // 4*32*64*64 u32 = 2 MB
    ushort_t* qp = (ushort_t*)(mbits + (size_t)4 * 32 * 64 * 64);
    ushort_t* kp = qp + E;
    ushort_t* vTp = kp + E;   // [512][8192]
    ushort_t* po = vTp + E;   // bf16, 2*4*2048*512
    float* pl = (float*)(po + (size_t)2 * 4 * 2048 * 512);  // 2*4*8*2048 fp32

    prep_all<<<dim3(15360), 256, 0, stream>>>(query, key_, value, Wq, Wk, Wv, Wo,
                                              mask, qb, kb, vb, Wqb, Wkb, Wvb, Wob,
                                              mbits);

    gemm_qkv<<<dim3(64, 4, 3), 256, 0, stream>>>(qb, kb, vb, Wqb, Wkb, Wvb,
                                                 bq, bk, bv, qp, kp, vTp);

    attn<<<dim3(16, 8, 8), 256, 0, stream>>>(qp, kp, vTp, mbits, po, pl);

    gemm_out<<<dim3(64, 8), 256, 0, stream>>>(po, pl, Wob, bo, (float*)d_out);
}

// Round 8
// 257.852 us; speedup vs baseline: 1.2369x; 1.0161x over previous
//
#include <hip/hip_runtime.h>

typedef unsigned short ushort_t;
typedef unsigned int u32;
typedef unsigned long long u64;
typedef __attribute__((ext_vector_type(4))) float f32x4;
typedef __attribute__((ext_vector_type(16))) float f32x16;
typedef __attribute__((ext_vector_type(8))) short s16x8;

__device__ __forceinline__ ushort_t f2bf(float f) {
    u32 u = __float_as_uint(f);
    u32 r = u + 0x7fffu + ((u >> 16) & 1u);
    return (ushort_t)(r >> 16);
}
__device__ __forceinline__ void cp16(const void* g, void* l) {
    __builtin_amdgcn_global_load_lds(
        (const __attribute__((address_space(1))) u32*)g,
        (__attribute__((address_space(3))) u32*)l, 16, 0, 0);
}

// ---------------- fused prep: bf16 casts + bit-mask, one launch ----------------
__global__ __launch_bounds__(256)
void prep_all(const float* __restrict__ qf, const float* __restrict__ kf,
              const float* __restrict__ vf, const float* __restrict__ Wq,
              const float* __restrict__ Wk, const float* __restrict__ Wv,
              const float* __restrict__ Wo, const int* __restrict__ m,
              ushort_t* __restrict__ oq, ushort_t* __restrict__ ok,
              ushort_t* __restrict__ ov, ushort_t* __restrict__ oWq,
              ushort_t* __restrict__ oWk, ushort_t* __restrict__ oWv,
              ushort_t* __restrict__ oWo, u32* __restrict__ mf) {
    const int bid = blockIdx.x;
    const int tid = threadIdx.x;
    if (bid < 13312) {
        const float* s; ushort_t* o; int i;
        if (bid < 12288) {
            const int part = bid >> 12, bx = bid & 4095;
            s = part == 0 ? qf : (part == 1 ? kf : vf);
            o = part == 0 ? oq : (part == 1 ? ok : ov);
            i = (bx * 256 + tid) * 4;
        } else {
            const int r = bid - 12288;
            const int part = r >> 8, bx = r & 255;
            s = part == 0 ? Wq : (part == 1 ? Wk : (part == 2 ? Wv : Wo));
            o = part == 0 ? oWq : (part == 1 ? oWk : (part == 2 ? oWv : oWo));
            i = (bx * 256 + tid) * 4;
        }
        float4 v = *(const float4*)(s + i);
        u64 pk = (u64)f2bf(v.x) | ((u64)f2bf(v.y) << 16) |
                 ((u64)f2bf(v.z) << 32) | ((u64)f2bf(v.w) << 48);
        *(u64*)(o + i) = pk;
    } else {
        // mask -> fragment-ordered bits: u32 per (b, kt64, g32=q/32, lane)
        __shared__ u32 ms32[128 * 20];
        const int r = bid - 13312;
        const int kt = r & 31, qt = (r >> 5) & 15, b = r >> 9;
        const int* mg = m + ((size_t)(b * 2048 + qt * 128)) * 2048 + kt * 64;
#pragma unroll
        for (int rep = 0; rep < 8; rep++) {
            int linear = rep * 256 + tid;
            int row = linear >> 4, ci = linear & 15;
            int4 v = *(const int4*)(mg + (size_t)row * 2048 + ci * 4);
            u32 w = (v.x ? 1u : 0u) | (v.y ? 0x100u : 0u) |
                    (v.z ? 0x10000u : 0u) | (v.w ? 0x1000000u : 0u);
            ms32[row * 20 + ci] = w;
        }
        __syncthreads();
        const int qgl = tid >> 6, L = tid & 63, hf = L >> 5, q5 = L & 31;
        const int row = qgl * 32 + q5;
        u32 rw[16];
#pragma unroll
        for (int j = 0; j < 4; j++) {
            uint4 t = *(const uint4*)&ms32[row * 20 + j * 4];
            rw[j * 4] = t.x; rw[j * 4 + 1] = t.y; rw[j * 4 + 2] = t.z; rw[j * 4 + 3] = t.w;
        }
        u32 res = 0;
#pragma unroll
        for (int mi = 0; mi < 16; mi++)
#pragma unroll
            for (int p = 0; p < 2; p++) {
                const int widx = 8 * (mi >> 3) + 2 * ((mi >> 1) & 3) + hf;
                const int shift = 8 * (2 * (mi & 1) + p);
                res |= ((rw[widx] >> shift) & 1u) << (2 * mi + p);
            }
        mf[(((size_t)b * 32 + kt) * 64 + qt * 4 + qgl) * 64 + L] = res;
    }
}

// ---------------- fused q/k/v projection: 128x128 NT GEMM ----------------
// z=0: q scaled by 0.125*log2(e), [B,H,S,64]; z=1: k [B,H,S,64]
// z=2: vT = Wv x^T stored [512][8192], kpos-axis sigma-permuted (swap 4-blocks
//      1<->2 within each 16) so attn's PV B-frag = raw C regs (no shuffle).
__global__ __launch_bounds__(256)
void gemm_qkv(const ushort_t* __restrict__ Aq, const ushort_t* __restrict__ Ak,
              const ushort_t* __restrict__ Av, const ushort_t* __restrict__ Wq,
              const ushort_t* __restrict__ Wk, const ushort_t* __restrict__ Wv,
              const float* __restrict__ bq, const float* __restrict__ bk,
              const float* __restrict__ bv, ushort_t* __restrict__ oq,
              ushort_t* __restrict__ ok, ushort_t* __restrict__ ov) {
    constexpr int K = 512;
    const int z = blockIdx.z;
    const ushort_t* A = z == 0 ? Aq : (z == 1 ? Ak : Wv);
    const ushort_t* Bm = z == 0 ? Wq : (z == 1 ? Wk : Av);
    const float* bias = z == 0 ? bq : (z == 1 ? bk : bv);
    ushort_t* out = z == 0 ? oq : (z == 1 ? ok : ov);
    const float scale = z == 0 ? 0.18033688f : 1.0f;  // 0.125*log2(e)
    const int bm = (z == 2) ? blockIdx.y : blockIdx.x;
    const int bn = (z == 2) ? blockIdx.x : blockIdx.y;

    __shared__ ushort_t As[128 * 32];
    __shared__ ushort_t Bs[128 * 32];
    const int tid = threadIdx.x;
    const int wave = tid >> 6, lane = tid & 63, quad = lane >> 4, l16 = lane & 15;
    const int wm = (wave >> 1) * 64, wn = (wave & 1) * 64;

    const ushort_t* Ag = A + (size_t)(bm * 128 + (tid >> 2)) * K + (tid & 3) * 8;
    const ushort_t* Bg = Bm + (size_t)(bn * 128 + (tid >> 2)) * K + (tid & 3) * 8;

    f32x4 acc[4][4];
#pragma unroll
    for (int i = 0; i < 4; i++)
#pragma unroll
        for (int j = 0; j < 4; j++) acc[i][j] = (f32x4){0.f, 0.f, 0.f, 0.f};

    for (int kt = 0; kt < K; kt += 32) {
        __syncthreads();
        cp16(Ag + kt, (char*)As + tid * 16);
        cp16(Ag + 64 * K + kt, (char*)As + 4096 + tid * 16);
        cp16(Bg + kt, (char*)Bs + tid * 16);
        cp16(Bg + 64 * K + kt, (char*)Bs + 4096 + tid * 16);
        __syncthreads();
        s16x8 af[4], bf[4];
#pragma unroll
        for (int i = 0; i < 4; i++)
            af[i] = *(const s16x8*)&As[(wm + i * 16 + l16) * 32 + quad * 8];
#pragma unroll
        for (int j = 0; j < 4; j++)
            bf[j] = *(const s16x8*)&Bs[(wn + j * 16 + l16) * 32 + quad * 8];
#pragma unroll
        for (int i = 0; i < 4; i++)
#pragma unroll
            for (int j = 0; j < 4; j++)
                acc[i][j] = __builtin_amdgcn_mfma_f32_16x16x32_bf16(af[i], bf[j], acc[i][j], 0, 0, 0);
    }

    if (z == 2) {
        // sigma permutation on the kpos (column) axis within each 16-group
        const int blk = (l16 >> 2) & 3;
        const int l16p = (blk == 1 || blk == 2) ? (l16 ^ 12) : l16;
#pragma unroll
        for (int i = 0; i < 4; i++) {
            const int gm0 = bm * 128 + wm + i * 16 + quad * 4;
            const float4 b4 = *(const float4*)&bias[gm0];
#pragma unroll
            for (int j = 0; j < 4; j++) {
                const int gn = bn * 128 + wn + j * 16 + l16p;
                out[(size_t)(gm0 + 0) * 8192 + gn] = f2bf(acc[i][j][0] + b4.x);
                out[(size_t)(gm0 + 1) * 8192 + gn] = f2bf(acc[i][j][1] + b4.y);
                out[(size_t)(gm0 + 2) * 8192 + gn] = f2bf(acc[i][j][2] + b4.z);
                out[(size_t)(gm0 + 3) * 8192 + gn] = f2bf(acc[i][j][3] + b4.w);
            }
        }
    } else {
#pragma unroll
        for (int j = 0; j < 4; j++) {
            const int gn = bn * 128 + wn + j * 16 + l16;
            const float bb = bias[gn];
            const int hh = gn >> 6, dd = gn & 63;
#pragma unroll
            for (int i = 0; i < 4; i++) {
                const int gm0 = bm * 128 + wm + i * 16 + quad * 4;
                const int bi = gm0 >> 11, s0 = gm0 & 2047;
#pragma unroll
                for (int p = 0; p < 4; p++)
                    out[(((size_t)(bi * 8 + hh)) * 2048 + s0 + p) * 64 + dd] =
                        f2bf((acc[i][j][p] + bb) * scale);
            }
        }
    }
}

// ---------------- fused attention: sigma-permuted V, no P shuffle ----------------
// grid (16 qt128, 8 h, 4b*2ks), 256 thr / 4 waves. Wave owns 32 q (q = lane&31).
__global__ __launch_bounds__(256, 4)
void attn(const ushort_t* __restrict__ q, const ushort_t* __restrict__ k,
          const ushort_t* __restrict__ vT, const u32* __restrict__ mf,
          ushort_t* __restrict__ po, float* __restrict__ pl) {
    __shared__ ushort_t Ks[2][64 * 64];  // double-buffered, XOR chunk-swizzled
    __shared__ ushort_t Vs[2][64 * 64];

    const int tid = threadIdx.x;
    const int qt = blockIdx.x, hh = blockIdx.y;
    const int b = blockIdx.z >> 1, ks = blockIdx.z & 1;
    const int w = tid >> 6, L = tid & 63, hf = L >> 5, q5 = L & 31;
    const size_t bh = (size_t)b * 8 + hh;
    const ushort_t* qg = q + (bh * 2048 + qt * 128 + w * 32) * 64;
    const ushort_t* kg = k + bh * 2048 * 64 + (size_t)ks * 65536;
    const ushort_t* vg = vT + (size_t)hh * 64 * 8192 + b * 2048 + ks * 1024;
    const u32* mg = mf + (((size_t)b * 32 + ks * 16) * 64 + qt * 4 + w) * 64 + L;

    const int lin0 = tid, lin1 = 256 + tid;
    const int sr0 = lin0 >> 3, sc0 = lin0 & 7;
    const int sr1 = lin1 >> 3, sc1 = lin1 & 7;
    const int kc0 = (sc0 ^ (sr0 & 7)) * 8, kc1 = (sc1 ^ (sr1 & 7)) * 8;

    cp16(kg + (size_t)sr0 * 64 + kc0, (char*)Ks[0] + lin0 * 16);
    cp16(kg + (size_t)sr1 * 64 + kc1, (char*)Ks[0] + lin1 * 16);
    cp16(vg + (size_t)sr0 * 8192 + kc0, (char*)Vs[0] + lin0 * 16);
    cp16(vg + (size_t)sr1 * 8192 + kc1, (char*)Vs[0] + lin1 * 16);

    s16x8 Qf[4];
#pragma unroll
    for (int s = 0; s < 4; s++)
        Qf[s] = *(const s16x8*)(qg + q5 * 64 + s * 16 + hf * 8);

    f32x16 O0, O1;
#pragma unroll
    for (int i = 0; i < 16; i++) { O0[i] = 0.f; O1[i] = 0.f; }
    float rsl = 0.f;

    for (int it = 0; it < 16; ++it) {
        const int cur = it & 1;
        __syncthreads();  // buffer[cur] staged
        if (it + 1 < 16) {
            const ushort_t* kn = kg + (size_t)(it + 1) * 4096;
            const ushort_t* vn = vg + (size_t)(it + 1) * 64;
            cp16(kn + (size_t)sr0 * 64 + kc0, (char*)Ks[1 - cur] + lin0 * 16);
            cp16(kn + (size_t)sr1 * 64 + kc1, (char*)Ks[1 - cur] + lin1 * 16);
            cp16(vn + (size_t)sr0 * 8192 + kc0, (char*)Vs[1 - cur] + lin0 * 16);
            cp16(vn + (size_t)sr1 * 8192 + kc1, (char*)Vs[1 - cur] + lin1 * 16);
        }

        const u32 mm = mg[(size_t)it * 4096];  // bit mask, L2-hot (2 MB total)

        f32x16 c0, c1;
#pragma unroll
        for (int i = 0; i < 16; i++) { c0[i] = 0.f; c1[i] = 0.f; }
#pragma unroll
        for (int s = 0; s < 4; s++) {
            const s16x8 kf0 = *(const s16x8*)&Ks[cur][q5 * 64 + (((2 * s + hf) ^ (q5 & 7)) * 8)];
            c0 = __builtin_amdgcn_mfma_f32_32x32x16_bf16(kf0, Qf[s], c0, 0, 0, 0);
        }
#pragma unroll
        for (int s = 0; s < 4; s++) {
            const s16x8 kf1 = *(const s16x8*)&Ks[cur][(32 + q5) * 64 + (((2 * s + hf) ^ (q5 & 7)) * 8)];
            c1 = __builtin_amdgcn_mfma_f32_32x32x16_bf16(kf1, Qf[s], c1, 0, 0, 0);
        }

        u32 P[16];
#pragma unroll
        for (int mi = 0; mi < 16; mi++) {
            const int reg = ((mi >> 1) & 3) * 4 + (mi & 1) * 2;
            const u32 am0 = (u32)__builtin_amdgcn_sbfe((int)mm, 2 * mi, 1);
            const u32 am1 = (u32)__builtin_amdgcn_sbfe((int)mm, 2 * mi + 1, 1);
            const float s0 = (mi < 8) ? c0[reg] : c1[reg];
            const float s1 = (mi < 8) ? c0[reg + 1] : c1[reg + 1];
            const u32 e0 = __float_as_uint(__builtin_amdgcn_exp2f(s0)) & am0;
            const u32 e1 = __float_as_uint(__builtin_amdgcn_exp2f(s1)) & am1;
            rsl += __uint_as_float(e0) + __uint_as_float(e1);
            // truncating bf16 pair pack: low = e0>>16, high = e1 top bits
            P[mi] = __builtin_amdgcn_perm(e1, e0, 0x07060302);
        }

        // O^T += V^T P^T : V is sigma-permuted in global, so B-frag = raw P regs
#pragma unroll
        for (int s = 0; s < 4; s++) {
            union { uint4 u; s16x8 v; } pu;
            pu.u.x = P[4 * s];
            pu.u.y = P[4 * s + 1];
            pu.u.z = P[4 * s + 2];
            pu.u.w = P[4 * s + 3];
            const s16x8 Pf = pu.v;
            const s16x8 vf0 = *(const s16x8*)&Vs[cur][q5 * 64 + (((2 * s + hf) ^ (q5 & 7)) * 8)];
            const s16x8 vf1 = *(const s16x8*)&Vs[cur][(32 + q5) * 64 + (((2 * s + hf) ^ (q5 & 7)) * 8)];
            O0 = __builtin_amdgcn_mfma_f32_32x32x16_bf16(vf0, Pf, O0, 0, 0, 0);
            O1 = __builtin_amdgcn_mfma_f32_32x32x16_bf16(vf1, Pf, O1, 0, 0, 0);
        }
    }

    const float rst = rsl + __shfl_xor(rsl, 32);
    const int qrow = qt * 128 + w * 32 + q5;
    if (hf == 0)
        pl[(((size_t)ks * 4 + b) * 8 + hh) * 2048 + qrow] = rst;
    ushort_t* por = po + ((size_t)(ks * 4 + b) * 2048 + qrow) * 512 + hh * 64;
#pragma unroll
    for (int dh = 0; dh < 2; dh++)
#pragma unroll
        for (int r4 = 0; r4 < 4; r4++) {
            const int d = dh * 32 + r4 * 8 + hf * 4;
            const float v0 = dh ? O1[r4 * 4 + 0] : O0[r4 * 4 + 0];
            const float v1 = dh ? O1[r4 * 4 + 1] : O0[r4 * 4 + 1];
            const float v2 = dh ? O1[r4 * 4 + 2] : O0[r4 * 4 + 2];
            const float v3 = dh ? O1[r4 * 4 + 3] : O0[r4 * 4 + 3];
            u32 lo = (u32)f2bf(v0) | ((u32)f2bf(v1) << 16);
            u32 hi = (u32)f2bf(v2) | ((u32)f2bf(v3) << 16);
            *(uint2*)(por + d) = make_uint2(lo, hi);
        }
}

// ---------------- output projection with fused split-K combine ----------------
__global__ __launch_bounds__(256)
void gemm_out(const ushort_t* __restrict__ po, const float* __restrict__ pl,
              const ushort_t* __restrict__ W, const float* __restrict__ bias,
              float* __restrict__ out) {
    __shared__ ushort_t As[128 * 32];
    __shared__ ushort_t Bs[64 * 32];
    __shared__ float lls[8 * 128];
    const int tid = threadIdx.x, bm = blockIdx.x, bn = blockIdx.y;
    const int wave = tid >> 6, lane = tid & 63, quad = lane >> 4, l16 = lane & 15;

#pragma unroll
    for (int rep = 0; rep < 4; rep++) {
        const int idx = rep * 256 + tid;
        const int h = idx >> 7, r = idx & 127;
        const int gm = bm * 128 + r, b = gm >> 11, s = gm & 2047;
        const float l0 = pl[((size_t)b * 8 + h) * 2048 + s];
        const float l1 = pl[((size_t)(4 + b) * 8 + h) * 2048 + s];
        lls[idx] = 1.0f / (l0 + l1);
    }

    const ushort_t* Bg = W + (size_t)(bn * 64 + (tid >> 2)) * 512 + (tid & 3) * 8;
    const int r0 = tid >> 2, c8 = (tid & 3) * 8;

    f32x4 acc[2][4];
#pragma unroll
    for (int i = 0; i < 2; i++)
#pragma unroll
        for (int j = 0; j < 4; j++) acc[i][j] = (f32x4){0.f, 0.f, 0.f, 0.f};

    for (int kt = 0; kt < 512; kt += 32) {
        __syncthreads();
        cp16(Bg + kt, (char*)Bs + tid * 16);
        const int hidx = kt >> 6;
#pragma unroll
        for (int half = 0; half < 2; half++) {
            const int r = r0 + half * 64;
            const ushort_t* p0 = po + (size_t)(bm * 128 + r) * 512 + kt + c8;
            const ushort_t* p1 = p0 + (size_t)4 * 2048 * 512;
            const uint4 ua = *(const uint4*)p0;
            const uint4 ub = *(const uint4*)p1;
            const float inv = lls[hidx * 128 + r];
            const u32 xa[4] = {ua.x, ua.y, ua.z, ua.w};
            const u32 xb[4] = {ub.x, ub.y, ub.z, ub.w};
            u32 wo[4];
#pragma unroll
            for (int j = 0; j < 4; j++) {
                const float lo = (__uint_as_float(xa[j] << 16) +
                                  __uint_as_float(xb[j] << 16)) * inv;
                const float hi = (__uint_as_float(xa[j] & 0xffff0000u) +
                                  __uint_as_float(xb[j] & 0xffff0000u)) * inv;
                wo[j] = (u32)f2bf(lo) | ((u32)f2bf(hi) << 16);
            }
            *(uint4*)&As[r * 32 + c8] = make_uint4(wo[0], wo[1], wo[2], wo[3]);
        }
        __syncthreads();
        s16x8 af[2], bf[4];
#pragma unroll
        for (int i = 0; i < 2; i++)
            af[i] = *(const s16x8*)&As[(wave * 32 + i * 16 + l16) * 32 + quad * 8];
#pragma unroll
        for (int j = 0; j < 4; j++)
            bf[j] = *(const s16x8*)&Bs[(j * 16 + l16) * 32 + quad * 8];
#pragma unroll
        for (int i = 0; i < 2; i++)
#pragma unroll
            for (int j = 0; j < 4; j++)
                acc[i][j] = __builtin_amdgcn_mfma_f32_16x16x32_bf16(af[i], bf[j], acc[i][j], 0, 0, 0);
    }

#pragma unroll
    for (int j = 0; j < 4; j++) {
        const int gn = bn * 64 + j * 16 + l16;
        const float bb = bias[gn];
#pragma unroll
        for (int i = 0; i < 2; i++) {
            const int gm0 = bm * 128 + wave * 32 + i * 16 + quad * 4;
#pragma unroll
            for (int p = 0; p < 4; p++)
                out[(size_t)(gm0 + p) * 512 + gn] = acc[i][j][p] + bb;
        }
    }
}

// ---------------- launch ----------------
extern "C" void kernel_launch(void* const* d_in, const int* in_sizes, int n_in,
                              void* d_out, int out_size, void* d_ws, size_t ws_size,
                              hipStream_t stream) {
    const float* query = (const float*)d_in[0];
    const float* key_ = (const float*)d_in[1];
    const float* value = (const float*)d_in[2];
    const int* mask = (const int*)d_in[3];
    const float* Wq = (const float*)d_in[4];
    const float* bq = (const float*)d_in[5];
    const float* Wk = (const float*)d_in[6];
    const float* bk = (const float*)d_in[7];
    const float* Wv = (const float*)d_in[8];
    const float* bv = (const float*)d_in[9];
    const float* Wo = (const float*)d_in[10];
    const float* bo = (const float*)d_in[11];

    const size_t E = 4194304;  // 8192*512
    const size_t W = 262144;   // 512*512
    ushort_t* qb = (ushort_t*)d_ws;
    ushort_t* kb = qb + E;
    ushort_t* vb = kb + E;
    ushort_t* Wqb = vb + E;
    ushort_t* Wkb = Wqb + W;
    ushort_t* Wvb = Wkb + W;
    ushort_t* Wob = Wvb + W;
    u32* mbits = (u32*)(Wob + W);              // 2 MB
    ushort_t* qp = (ushort_t*)(mbits + (size_t)4 * 32 * 64 * 64);
    ushort_t* kp = qp + E;
    ushort_t* vTp = kp + E;   // [512][8192], sigma-permuted kpos
    ushort_t* po = vTp + E;   // bf16 partials, 2*4*2048*512
    float* pl = (float*)(po + (size_t)2 * 4 * 2048 * 512);

    prep_all<<<dim3(15360), 256, 0, stream>>>(query, key_, value, Wq, Wk, Wv, Wo,
                                              mask, qb, kb, vb, Wqb, Wkb, Wvb, Wob,
                                              mbits);

    gemm_qkv<<<dim3(64, 4, 3), 256, 0, stream>>>(qb, kb, vb, Wqb, Wkb, Wvb,
                                                 bq, bk, bv, qp, kp, vTp);

    attn<<<dim3(16, 8, 8), 256, 0, stream>>>(qp, kp, vTp, mbits, po, pl);

    gemm_out<<<dim3(64, 8), 256, 0, stream>>>(po, pl, Wob, bo, (float*)d_out);
}